// Round 1
// baseline (33.314 us; speedup 1.0000x reference)
//
#include <hip/hip_runtime.h>
#include <math.h>

#define NELEM   8192
#define BLK     256
#define JCHUNK  1024
#define JBLOCKS (NELEM / JCHUNK)   // 8
#define IBLOCKS (NELEM / BLK)      // 32

// Each block: i-range [blockIdx.x*256, +256), j-range [blockIdx.y*1024, +1024).
// Counts pairs with time[j] < time[i] && event[j]  (den) and additionally
// risk[j] > risk[i]  (num). Exact integer counting; packed u64 accumulation.
__global__ __launch_bounds__(BLK) void ci_pair_kernel(
    const float* __restrict__ risk,
    const float* __restrict__ time_,
    const float* __restrict__ event_,
    unsigned long long* __restrict__ ws)
{
    __shared__ float s_tm[JCHUNK];   // time[j] if event[j] else +INF
    __shared__ float s_r [JCHUNK];   // risk[j]

    const int   i  = blockIdx.x * BLK + threadIdx.x;
    const float ti = time_[i];
    const float ri = risk[i];

    const int jbase = blockIdx.y * JCHUNK;
    #pragma unroll
    for (int k = threadIdx.x; k < JCHUNK; k += BLK) {
        float e = event_[jbase + k];
        float t = time_[jbase + k];
        s_tm[k] = (e > 0.0f) ? t : __builtin_inff();  // INF never < finite ti
        s_r[k]  = risk[jbase + k];
    }
    __syncthreads();

    unsigned num = 0, den = 0;
    #pragma unroll 8
    for (int k = 0; k < JCHUNK; ++k) {
        bool c = (s_tm[k] < ti);               // event[j] && time[j] < time[i]
        den += c ? 1u : 0u;
        num += (c && (s_r[k] > ri)) ? 1u : 0u; // ... && risk[j] > risk[i]
    }

    // pack: high32 = den, low32 = num. Totals < 2^32 each (max 33.5M pairs),
    // so low-word accumulation never carries into the high word.
    unsigned long long packed =
        ((unsigned long long)den << 32) | (unsigned long long)num;

    // wave64 butterfly-free down-reduce
    for (int off = 32; off > 0; off >>= 1)
        packed += __shfl_down(packed, off);

    __shared__ unsigned long long s_part[BLK / 64];
    const int lane = threadIdx.x & 63;
    const int wave = threadIdx.x >> 6;
    if (lane == 0) s_part[wave] = packed;
    __syncthreads();
    if (threadIdx.x == 0) {
        unsigned long long tot = 0;
        #pragma unroll
        for (int w = 0; w < BLK / 64; ++w) tot += s_part[w];
        atomicAdd(ws, tot);   // device-scope by default on CDNA
    }
}

__global__ void ci_finalize_kernel(const unsigned long long* __restrict__ ws,
                                   float* __restrict__ out)
{
    unsigned long long v = *ws;
    unsigned num = (unsigned)(v & 0xffffffffULL);
    unsigned den = (unsigned)(v >> 32);
    out[0] = den ? (float)((double)num / (double)den) : __builtin_nanf("");
}

extern "C" void kernel_launch(void* const* d_in, const int* in_sizes, int n_in,
                              void* d_out, int out_size, void* d_ws, size_t ws_size,
                              hipStream_t stream) {
    const float* risk   = (const float*)d_in[0];
    const float* time_  = (const float*)d_in[1];
    const float* event_ = (const float*)d_in[2];
    float* out = (float*)d_out;
    unsigned long long* ws = (unsigned long long*)d_ws;

    // ws is poisoned 0xAA once and never re-poisoned; zero it every call.
    hipMemsetAsync(ws, 0, sizeof(unsigned long long), stream);

    dim3 grid(IBLOCKS, JBLOCKS);
    ci_pair_kernel<<<grid, BLK, 0, stream>>>(risk, time_, event_, ws);
    ci_finalize_kernel<<<1, 1, 0, stream>>>(ws, out);
}

// Round 2
// 19.139 us; speedup vs baseline: 1.7406x; 1.7406x over previous
//
#include <hip/hip_runtime.h>
#include <math.h>

#define NELEM   8192
#define BLK     256
#define JCHUNK  512
#define IBLOCKS (NELEM / BLK)      // 32
#define JBLOCKS (NELEM / JCHUNK)   // 16
#define NPART   (IBLOCKS * JBLOCKS) // 512 partials, 4 KB of ws

// Pair-count kernel. Block (bx,by) handles i in [bx*256, +256), j in [by*512, +512).
//   den += (event[j] && time[j] < time[i])
//   num += (event[j] && time[j] < time[i] && risk[j] > risk[i])
// Event mask is folded into staged time (non-events get +INF, never < any finite ti).
// Partial (den<<32 | num) is written per block -- no atomics, no ws pre-zeroing.
__global__ __launch_bounds__(BLK) void ci_pair_kernel(
    const float* __restrict__ risk,
    const float* __restrict__ time_,
    const float* __restrict__ event_,
    unsigned long long* __restrict__ ws)
{
    __shared__ __align__(16) float2 s[JCHUNK];   // (masked_time, risk)

    const int   i  = blockIdx.x * BLK + threadIdx.x;
    const float ti = time_[i];
    const float ri = risk[i];

    const int jbase = blockIdx.y * JCHUNK;
    #pragma unroll
    for (int k = threadIdx.x; k < JCHUNK; k += BLK) {
        float e = event_[jbase + k];
        float t = time_[jbase + k];
        s[k] = make_float2((e > 0.0f) ? t : __builtin_inff(), risk[jbase + k]);
    }
    __syncthreads();

    unsigned num = 0, den = 0;
    const float4* s4 = (const float4*)s;   // 2 (time,risk) pairs per ds_read_b128
    #pragma unroll 8
    for (int kk = 0; kk < JCHUNK / 2; ++kk) {
        float4 w = s4[kk];
        bool c0 = (w.x < ti);
        bool g0 = (w.y > ri);
        den += c0 ? 1u : 0u;
        num += (c0 && g0) ? 1u : 0u;
        bool c1 = (w.z < ti);
        bool g1 = (w.w > ri);
        den += c1 ? 1u : 0u;
        num += (c1 && g1) ? 1u : 0u;
    }

    // pack high32=den low32=num; per-block totals << 2^32, no carry into high word
    unsigned long long packed =
        ((unsigned long long)den << 32) | (unsigned long long)num;

    for (int off = 32; off > 0; off >>= 1)
        packed += __shfl_down(packed, off);

    __shared__ unsigned long long s_part[BLK / 64];
    const int lane = threadIdx.x & 63;
    const int wave = threadIdx.x >> 6;
    if (lane == 0) s_part[wave] = packed;
    __syncthreads();
    if (threadIdx.x == 0) {
        unsigned long long tot = 0;
        #pragma unroll
        for (int w = 0; w < BLK / 64; ++w) tot += s_part[w];
        ws[blockIdx.y * IBLOCKS + blockIdx.x] = tot;   // pure write, deterministic
    }
}

// Reduce 512 partials -> final ratio. One block, 256 threads.
__global__ __launch_bounds__(256) void ci_reduce_kernel(
    const unsigned long long* __restrict__ ws,
    float* __restrict__ out)
{
    unsigned long long v = ws[threadIdx.x] + ws[threadIdx.x + 256];
    for (int off = 32; off > 0; off >>= 1)
        v += __shfl_down(v, off);

    __shared__ unsigned long long s_part[4];
    const int lane = threadIdx.x & 63;
    const int wave = threadIdx.x >> 6;
    if (lane == 0) s_part[wave] = v;
    __syncthreads();
    if (threadIdx.x == 0) {
        unsigned long long tot = s_part[0] + s_part[1] + s_part[2] + s_part[3];
        unsigned num = (unsigned)(tot & 0xffffffffULL);
        unsigned den = (unsigned)(tot >> 32);
        out[0] = den ? (float)((double)num / (double)den) : __builtin_nanf("");
    }
}

extern "C" void kernel_launch(void* const* d_in, const int* in_sizes, int n_in,
                              void* d_out, int out_size, void* d_ws, size_t ws_size,
                              hipStream_t stream) {
    const float* risk   = (const float*)d_in[0];
    const float* time_  = (const float*)d_in[1];
    const float* event_ = (const float*)d_in[2];
    float* out = (float*)d_out;
    unsigned long long* ws = (unsigned long long*)d_ws;

    dim3 grid(IBLOCKS, JBLOCKS);   // 512 blocks = 2 per CU
    ci_pair_kernel<<<grid, BLK, 0, stream>>>(risk, time_, event_, ws);
    ci_reduce_kernel<<<1, 256, 0, stream>>>(ws, out);
}